// Round 7
// baseline (149.111 us; speedup 1.0000x reference)
//
#include <hip/hip_runtime.h>
#include <hip/hip_cooperative_groups.h>
#include <math.h>

namespace cg = cooperative_groups;

// Problem constants:
//   x:  (256, 197, 384) f32   — row 0 is CLS, rows 1..196 are "nodes"
//   ea: (256, 196, 384) f32
//   out:(256, 50, 384)  f32   — [CLS, 49 selected nodes in ascending-score order]
#define NB      256
#define NNODES  196
#define NC      384
#define SEQ     197
#define START   147          // 196//4*3
#define KEEP    49
#define OUTROWS 50

#define NT      960          // 15 waves/block
#define RG      10
#define C4      96           // NC/4 float4 columns
#define HALF    98           // rows (P1) / nodes (P2) per half-block

// ws layout: wsum double[NB][2][NC] (1.57 MB) then wscore float[NB][NNODES] (200 KB)
#define WSUM_ELEMS ((size_t)NB * 2 * NC)

// ============== Cooperative 2-blocks-per-batch kernel =====================
// LDS: 15360 (partial f32) + 1536 (imp) + 784 (sc) + 196 (sel) ~= 17.9 KB
// -> 2 blocks/CU fits the 64 KB occupancy budget (round-6 fix).
__global__ __launch_bounds__(NT, 8)   // VGPR<=64 -> 2 blocks/CU co-resident
void pool_coop(const float* __restrict__ x,
               const float* __restrict__ ea,
               float* __restrict__ out,
               double* __restrict__ wsum,     // [NB][2][NC]
               float*  __restrict__ wscore) { // [NB][NNODES]
    __shared__ float partial[RG][NC];         // 15 KB (f32 partials)
    __shared__ alignas(16) float imp[NC];
    __shared__ float sc[NNODES];
    __shared__ int   sel[KEEP];

    const int gb  = blockIdx.x;
    const int b   = gb >> 1;
    const int h   = gb & 1;
    const int tid = threadIdx.x;              // 0..959

    // ---- Phase 1: column sums of this half's 98 ea-rows (f64 reg accum) ----
    {
        const int rg = tid / C4;              // 0..9
        const int c4 = tid % C4;
        const float4* p = (const float4*)(ea + (size_t)b * NNODES * NC) + c4;
        const int r0 = h * HALF;
        double ax = 0.0, ay = 0.0, az = 0.0, aw = 0.0;
        for (int row = rg; row < HALF; row += RG) {
            float4 v = p[(size_t)(r0 + row) * C4];   // coalesced
            ax += v.x; ay += v.y; az += v.z; aw += v.w;
        }
        partial[rg][4 * c4 + 0] = (float)ax;
        partial[rg][4 * c4 + 1] = (float)ay;
        partial[rg][4 * c4 + 2] = (float)az;
        partial[rg][4 * c4 + 3] = (float)aw;
    }
    __syncthreads();
    if (tid < NC) {
        double s = 0.0;
        #pragma unroll
        for (int rg = 0; rg < RG; ++rg) s += (double)partial[rg][tid];
        wsum[((size_t)b * 2 + h) * NC + tid] = s;    // deterministic half-sum
    }

    cg::this_grid().sync();   // half-sums visible device-wide

    // ---- Phase 2: imp from both halves (fixed order -> identical bits in
    //      both blocks), then score this half's 98 nodes ----
    if (tid < NC) {
        double s = wsum[((size_t)b * 2 + 0) * NC + tid]
                 + wsum[((size_t)b * 2 + 1) * NC + tid];
        float m = (float)(s * (1.0 / (double)NNODES));
        imp[tid] = 1.0f / (1.0f + expf(-m));
    }
    __syncthreads();

    {
        const int wave = tid >> 6;            // 0..14
        const int lane = tid & 63;
        const float* nodes = x + ((size_t)b * SEQ + 1) * NC;
        const float2* imp2 = (const float2*)imp;
        float2 w[3];
        #pragma unroll
        for (int j = 0; j < 3; ++j) w[j] = imp2[lane + 64 * j];

        const int n0 = h * HALF;
        for (int n = n0 + wave; n < n0 + HALF; n += 15) {
            const float2* row2 = (const float2*)(nodes + (size_t)n * NC);
            double acc = 0.0;
            #pragma unroll
            for (int j = 0; j < 3; ++j) {
                float2 v = row2[lane + 64 * j];          // coalesced
                acc += (double)v.x * (double)w[j].x + (double)v.y * (double)w[j].y;
            }
            #pragma unroll
            for (int off = 32; off > 0; off >>= 1)
                acc += __shfl_xor(acc, off);
            if (lane == 0) wscore[(size_t)b * NNODES + n] = (float)acc;
        }
    }

    cg::this_grid().sync();   // all 196 scores visible

    // ---- Phase 3: stable ascending rank (duplicated in both half-blocks) ----
    if (tid < NNODES) sc[tid] = wscore[(size_t)b * NNODES + tid];
    __syncthreads();
    if (tid < NNODES) {
        const float s = sc[tid];
        int rank = 0;
        for (int m = 0; m < NNODES; ++m) {
            const float sm = sc[m];
            rank += (sm < s) || (sm == s && m < tid);    // stable tie-break
        }
        if (rank >= START) sel[rank - START] = tid;
    }
    __syncthreads();

    // ---- Phase 4: block h writes out rows [25h, 25h+25) (float4) ----
    {
        const int jg = tid / C4;              // 0..9
        const int c4 = tid % C4;
        const float* nodes   = x + ((size_t)b * SEQ + 1) * NC;
        const float4* nodes4 = (const float4*)nodes;
        const float4* cls4   = (const float4*)(x + (size_t)b * SEQ * NC);
        float4* out4         = (float4*)(out + (size_t)b * OUTROWS * NC);
        #pragma unroll
        for (int it = 0; it < 3; ++it) {
            int jj = jg + RG * it;            // 0..29
            if (jj < 25) {
                int j = h * 25 + jj;          // 0..49
                const float4* src = (j == 0) ? cls4 : (nodes4 + (size_t)sel[j - 1] * C4);
                out4[(size_t)j * C4 + c4] = src[c4];
            }
        }
    }
}

// ============== Fallback: proven round-2 single-block kernel ==============
__global__ __launch_bounds__(NT)
void pooling_block_fallback(const float* __restrict__ x,
                            const float* __restrict__ ea,
                            float* __restrict__ out) {
    __shared__ double partial[RG][NC];
    __shared__ alignas(16) float imp[NC];
    __shared__ float scores[NNODES];
    __shared__ int   sel[KEEP];

    const int b   = blockIdx.x;
    const int tid = threadIdx.x;

    {
        const int rg = tid / C4;
        const int c4 = tid % C4;
        const float4* p = (const float4*)(ea + (size_t)b * NNODES * NC);
        double ax = 0.0, ay = 0.0, az = 0.0, aw = 0.0;
        for (int row = rg; row < NNODES; row += RG) {
            float4 v = p[(size_t)row * C4 + c4];
            ax += v.x; ay += v.y; az += v.z; aw += v.w;
        }
        partial[rg][4 * c4 + 0] = ax;
        partial[rg][4 * c4 + 1] = ay;
        partial[rg][4 * c4 + 2] = az;
        partial[rg][4 * c4 + 3] = aw;
    }
    __syncthreads();
    if (tid < NC) {
        double s = 0.0;
        #pragma unroll
        for (int rg = 0; rg < RG; ++rg) s += partial[rg][tid];
        float m = (float)(s * (1.0 / (double)NNODES));
        imp[tid] = 1.0f / (1.0f + expf(-m));
    }
    __syncthreads();

    const int wave = tid >> 6;
    const int lane = tid & 63;
    const float* nodes = x + ((size_t)b * SEQ + 1) * NC;

    for (int n = wave; n < NNODES; n += 15) {
        const float2* row2 = (const float2*)(nodes + (size_t)n * NC);
        const float2* imp2 = (const float2*)imp;
        double acc = 0.0;
        #pragma unroll
        for (int j = 0; j < 3; ++j) {
            int i = lane + 64 * j;
            float2 v = row2[i];
            float2 w = imp2[i];
            acc += (double)v.x * (double)w.x + (double)v.y * (double)w.y;
        }
        #pragma unroll
        for (int off = 32; off > 0; off >>= 1)
            acc += __shfl_xor(acc, off);
        if (lane == 0) scores[n] = (float)acc;
    }
    __syncthreads();

    if (tid < NNODES) {
        const float s = scores[tid];
        int rank = 0;
        for (int m = 0; m < NNODES; ++m) {
            const float sm = scores[m];
            rank += (sm < s) || (sm == s && m < tid);
        }
        if (rank >= START) sel[rank - START] = tid;
    }
    __syncthreads();

    {
        const int jg = tid / C4;
        const int c4 = tid % C4;
        const float4* nodes4 = (const float4*)nodes;
        const float4* cls4   = (const float4*)(x + (size_t)b * SEQ * NC);
        float4* out4         = (float4*)(out + (size_t)b * OUTROWS * NC);
        #pragma unroll
        for (int it = 0; it < 5; ++it) {
            int j = jg + 10 * it;
            const float4* src = (j == 0) ? cls4 : (nodes4 + (size_t)sel[j - 1] * C4);
            out4[(size_t)j * C4 + c4] = src[c4];
        }
    }
}

extern "C" void kernel_launch(void* const* d_in, const int* in_sizes, int n_in,
                              void* d_out, int out_size, void* d_ws, size_t ws_size,
                              hipStream_t stream) {
    const float* x  = (const float*)d_in[0];
    const float* ea = (const float*)d_in[1];
    float* out      = (float*)d_out;
    double* wsum    = (double*)d_ws;
    float*  wscore  = (float*)((char*)d_ws + WSUM_ELEMS * sizeof(double));

    void* args[] = { (void*)&x, (void*)&ea, (void*)&out, (void*)&wsum, (void*)&wscore };
    hipError_t err = hipLaunchCooperativeKernel(
        reinterpret_cast<void*>(pool_coop),
        dim3(NB * 2), dim3(NT), args, 0, stream);

    if (err != hipSuccess) {
        (void)hipGetLastError();   // clear sticky error; host-side only
        hipLaunchKernelGGL(pooling_block_fallback,
                           dim3(NB), dim3(NT), 0, stream, x, ea, out);
    }
}

// Round 8
// 40.489 us; speedup vs baseline: 3.6827x; 3.6827x over previous
//
#include <hip/hip_runtime.h>
#include <math.h>

// Problem constants:
//   x:  (256, 197, 384) f32   — row 0 is CLS, rows 1..196 are "nodes"
//   ea: (256, 196, 384) f32
//   out:(256, 50, 384)  f32   — [CLS, 49 selected nodes in ascending-score order]
#define NB      256
#define NNODES  196
#define NC      384
#define SEQ     197
#define START   147          // 196//4*3
#define KEEP    49
#define OUTROWS 50
#define C4      96           // NC/4 float4 columns

#define NT      960          // 15 waves, 1 block per batch
#define P1T     576          // waves 0..8: phase-1 ea column sums
#define P1RG    6            // row groups in phase 1 (576/96)
#define SROWS   88           // node rows staged in LDS by waves 9..14
#define SITERS  22           // (88*96 float4) / 384 threads

// LDS: stage 135168 + partial 9216 + imp 1536 + sc 784 + sel 196 ~= 147 KB
// (fits the 160 KB/CU of gfx950; occupancy stays 1 block/CU — round 7
// proved occupancy is not the lever, stream overlap is what we're buying)
__global__ __launch_bounds__(NT)
void pool_fused(const float* __restrict__ x,
                const float* __restrict__ ea,
                float* __restrict__ out) {
    __shared__ alignas(16) float stage[SROWS][NC];   // 132 KB x-row stage
    __shared__ float partial[P1RG][NC];              // f32 partials (9 KB)
    __shared__ alignas(16) float imp[NC];
    __shared__ float sc[NNODES];
    __shared__ int   sel[KEEP];

    const int b    = blockIdx.x;
    const int tid  = threadIdx.x;                    // 0..959
    const int wave = tid >> 6;
    const int lane = tid & 63;
    const float* nodes = x + ((size_t)b * SEQ + 1) * NC;   // skip CLS

    // ---- Concurrent phase 1: waves 0-8 stream ea, waves 9-14 stream x→LDS ----
    if (tid < P1T) {
        // ea column sums: rg = tid/96 (0..5), ~33 rows each, f64 reg accum
        const int rg = tid / C4;
        const int c4 = tid % C4;
        const float4* p = (const float4*)(ea + (size_t)b * NNODES * NC) + c4;
        double ax = 0.0, ay = 0.0, az = 0.0, aw = 0.0;
        for (int row = rg; row < NNODES; row += P1RG) {
            float4 v = p[(size_t)row * C4];          // coalesced
            ax += v.x; ay += v.y; az += v.z; aw += v.w;
        }
        partial[rg][4 * c4 + 0] = (float)ax;
        partial[rg][4 * c4 + 1] = (float)ay;
        partial[rg][4 * c4 + 2] = (float)az;
        partial[rg][4 * c4 + 3] = (float)aw;
    } else {
        // straight contiguous copy: node rows 0..87 -> LDS (float4, coalesced)
        const int t = tid - P1T;                     // 0..383
        const float4* src = (const float4*)nodes;
        float4* dst = (float4*)&stage[0][0];
        #pragma unroll
        for (int i = 0; i < SITERS; ++i)
            dst[t + 384 * i] = src[t + 384 * i];
    }
    __syncthreads();

    // ---- imp[c] = sigmoid(mean): fixed-order reduce (deterministic) ----
    if (tid < NC) {
        double s = 0.0;
        #pragma unroll
        for (int rg = 0; rg < P1RG; ++rg) s += (double)partial[rg][tid];
        float m = (float)(s * (1.0 / (double)NNODES));
        imp[tid] = 1.0f / (1.0f + expf(-m));
    }
    __syncthreads();

    // ---- Phase 2: wave-per-node dots; rows <SROWS from LDS, rest global ----
    {
        const float2* imp2 = (const float2*)imp;
        float2 w[3];
        #pragma unroll
        for (int j = 0; j < 3; ++j) w[j] = imp2[lane + 64 * j];

        for (int n = wave; n < NNODES; n += 15) {    // n uniform per wave
            double acc = 0.0;
            if (n < SROWS) {
                const float2* row2 = (const float2*)&stage[n][0];
                #pragma unroll
                for (int j = 0; j < 3; ++j) {
                    float2 v = row2[lane + 64 * j];  // ds_read, conflict-free
                    acc += (double)v.x * (double)w[j].x + (double)v.y * (double)w[j].y;
                }
            } else {
                const float2* row2 = (const float2*)(nodes + (size_t)n * NC);
                #pragma unroll
                for (int j = 0; j < 3; ++j) {
                    float2 v = row2[lane + 64 * j];  // coalesced global
                    acc += (double)v.x * (double)w[j].x + (double)v.y * (double)w[j].y;
                }
            }
            #pragma unroll
            for (int off = 32; off > 0; off >>= 1)
                acc += __shfl_xor(acc, off);
            if (lane == 0) sc[n] = (float)acc;
        }
    }
    __syncthreads();

    // ---- Phase 3: stable ascending rank; keep ranks >= START ----
    if (tid < NNODES) {
        const float s = sc[tid];
        int rank = 0;
        for (int m = 0; m < NNODES; ++m) {
            const float sm = sc[m];
            rank += (sm < s) || (sm == s && m < tid);   // stable tie-break
        }
        if (rank >= START) sel[rank - START] = tid;
    }
    __syncthreads();

    // ---- Phase 4: write output rows (float4; staged rows come from LDS) ----
    {
        const int jg = tid / C4;                     // 0..9
        const int c4 = tid % C4;
        const float4* nodes4 = (const float4*)nodes;
        const float4* cls4   = (const float4*)(x + (size_t)b * SEQ * NC);
        float4* out4         = (float4*)(out + (size_t)b * OUTROWS * NC);
        #pragma unroll
        for (int it = 0; it < 5; ++it) {
            int j = jg + 10 * it;                    // 0..49
            float4 v;
            if (j == 0) {
                v = cls4[c4];
            } else {
                int n = sel[j - 1];                  // uniform within iteration
                v = (n < SROWS) ? ((const float4*)&stage[n][0])[c4]
                                : nodes4[(size_t)n * C4 + c4];
            }
            out4[(size_t)j * C4 + c4] = v;
        }
    }
}

extern "C" void kernel_launch(void* const* d_in, const int* in_sizes, int n_in,
                              void* d_out, int out_size, void* d_ws, size_t ws_size,
                              hipStream_t stream) {
    const float* x  = (const float*)d_in[0];
    const float* ea = (const float*)d_in[1];
    float* out      = (float*)d_out;

    hipLaunchKernelGGL(pool_fused, dim3(NB), dim3(NT), 0, stream, x, ea, out);
}